// Round 6
// baseline (1817.159 us; speedup 1.0000x reference)
//
#include <hip/hip_runtime.h>
#include <math.h>

#define NN 50000
#define NE 640000

// ---------------- CSR build ----------------

__global__ void count_kernel(const int* __restrict__ dst, int* __restrict__ cnt, int E) {
    int e = blockIdx.x * blockDim.x + threadIdx.x;
    if (e < E) atomicAdd(&cnt[dst[e]], 1);
}

__global__ __launch_bounds__(256) void block_reduce_kernel(const int* __restrict__ cnt,
                                                           int* __restrict__ blk_sums, int N) {
    __shared__ int red[256];
    int tid = threadIdx.x;
    int base = blockIdx.x * 1024 + tid * 4;
    int s = 0;
    if (base + 3 < N) {
        int4 v = *reinterpret_cast<const int4*>(&cnt[base]);
        s = v.x + v.y + v.z + v.w;
    } else {
        for (int i = 0; i < 4; ++i)
            if (base + i < N) s += cnt[base + i];
    }
    red[tid] = s;
    __syncthreads();
    for (int off = 128; off > 0; off >>= 1) {
        if (tid < off) red[tid] += red[tid + off];
        __syncthreads();
    }
    if (tid == 0) blk_sums[blockIdx.x] = red[0];
}

__global__ __launch_bounds__(64) void scan_sums_kernel(int* __restrict__ blk_sums, int nblk) {
    int lane = threadIdx.x;
    int v = (lane < nblk) ? blk_sums[lane] : 0;
    for (int off = 1; off < 64; off <<= 1) {
        int u = __shfl_up(v, off);
        if (lane >= off) v += u;
    }
    int ex = __shfl_up(v, 1);
    if (lane == 0) ex = 0;
    if (lane < nblk) blk_sums[lane] = ex;
}

__global__ __launch_bounds__(256) void block_scan_kernel(const int* __restrict__ cnt,
                                                         const int* __restrict__ blk_offs,
                                                         int* __restrict__ row_ptr,
                                                         int* __restrict__ tmp_ptr,
                                                         float* __restrict__ dinv,
                                                         int N, int E) {
    __shared__ int warp_sums[4];
    int tid = threadIdx.x;
    int base = blockIdx.x * 1024 + tid * 4;
    int c[4];
    int s = 0;
#pragma unroll
    for (int i = 0; i < 4; ++i) {
        int idx = base + i;
        c[i] = (idx < N) ? cnt[idx] : 0;
        s += c[i];
    }
    int lane = tid & 63;
    int wv = tid >> 6;
    int v = s;
    for (int off = 1; off < 64; off <<= 1) {
        int u = __shfl_up(v, off);
        if (lane >= off) v += u;
    }
    if (lane == 63) warp_sums[wv] = v;
    __syncthreads();
    int woff = 0;
    for (int w = 0; w < wv; ++w) woff += warp_sums[w];
    int run = blk_offs[blockIdx.x] + woff + (v - s);
#pragma unroll
    for (int i = 0; i < 4; ++i) {
        int idx = base + i;
        if (idx < N) {
            row_ptr[idx] = run;
            tmp_ptr[idx] = run;
            run += c[i];
            dinv[idx] = rsqrtf((float)c[i] + 1.0f);
        }
    }
    if (blockIdx.x == 0 && tid == 0) row_ptr[N] = E;
}

__global__ void fill_kernel(const int* __restrict__ src, const int* __restrict__ dst,
                            int* __restrict__ tmp_ptr, int* __restrict__ col, int E) {
    int e = blockIdx.x * blockDim.x + threadIdx.x;
    if (e < E) {
        int d = dst[e];
        int pos = atomicAdd(&tmp_ptr[d], 1);
        col[pos] = src[e];
    }
}

// ---------------- GEMM: G[r][c] = dinv[r] * sum_k X[r][k] * W[k][c], K = 128 ----------------
// No LDS. 32 rows/block (grid ~1563 = ~6 blocks/CU), register double-buffered
// k-chunks (load chunk kc+1 while FMA-ing chunk kc). Fully unrolled so all
// buffer indices are compile-time (no scratch).

template <int NOUT>
__global__ __launch_bounds__(256) void gemm_scale_kernel(const float* __restrict__ X,
                                                         const float* __restrict__ W,
                                                         const float* __restrict__ dinv,
                                                         float* __restrict__ G, int N) {
    constexpr int K = 128;
    constexpr int TXN = NOUT / 4;               // lanes across columns: 32 (128) / 16 (64)
    constexpr int RPT = (NOUT == 128) ? 4 : 2;  // rows per thread
    constexpr int ROWS = (256 / TXN) * RPT;     // 32 rows per block

    int tid = threadIdx.x;
    int tx = tid % TXN;
    int ty = tid / TXN;
    int c0 = tx * 4;
    int r0 = blockIdx.x * ROWS + ty * RPT;

    const float* Xp[RPT];
#pragma unroll
    for (int j = 0; j < RPT; ++j) {
        int r = min(r0 + j, N - 1);  // clamp loads; stores guarded below
        Xp[j] = X + (size_t)r * K;
    }

    float acc[RPT][4];
#pragma unroll
    for (int j = 0; j < RPT; ++j)
#pragma unroll
        for (int c = 0; c < 4; ++c) acc[j][c] = 0.f;

    float4 xbuf[2][RPT];
    float4 wbuf[2][4];

#pragma unroll
    for (int j = 0; j < RPT; ++j) xbuf[0][j] = *reinterpret_cast<const float4*>(Xp[j] + 0);
#pragma unroll
    for (int kk = 0; kk < 4; ++kk)
        wbuf[0][kk] = *reinterpret_cast<const float4*>(&W[kk * NOUT + c0]);

#pragma unroll
    for (int kc = 0; kc < K / 4; ++kc) {
        const int cur = kc & 1;
        const int nxt = cur ^ 1;
        if (kc + 1 < K / 4) {
            int kn = (kc + 1) * 4;
#pragma unroll
            for (int j = 0; j < RPT; ++j)
                xbuf[nxt][j] = *reinterpret_cast<const float4*>(Xp[j] + kn);
#pragma unroll
            for (int kk = 0; kk < 4; ++kk)
                wbuf[nxt][kk] = *reinterpret_cast<const float4*>(&W[(kn + kk) * NOUT + c0]);
        }
#pragma unroll
        for (int kk = 0; kk < 4; ++kk) {
            const float4 wv = wbuf[cur][kk];
#pragma unroll
            for (int j = 0; j < RPT; ++j) {
                const float xs = reinterpret_cast<const float*>(&xbuf[cur][j])[kk];
                acc[j][0] = fmaf(xs, wv.x, acc[j][0]);
                acc[j][1] = fmaf(xs, wv.y, acc[j][1]);
                acc[j][2] = fmaf(xs, wv.z, acc[j][2]);
                acc[j][3] = fmaf(xs, wv.w, acc[j][3]);
            }
        }
    }

#pragma unroll
    for (int j = 0; j < RPT; ++j) {
        int r = r0 + j;
        if (r < N) {
            float s = dinv[r];
            float4 o;
            o.x = s * acc[j][0];
            o.y = s * acc[j][1];
            o.z = s * acc[j][2];
            o.w = s * acc[j][3];
            *reinterpret_cast<float4*>(&G[(size_t)r * NOUT + c0]) = o;
        }
    }
}

// ---------------- Aggregate: Out[i] = act(dinv[i]*(sum_{j in N(i)} G[j] + G[i]) + b) ----------------
// One wave per node; 8 gathers in flight (8 independent accumulators).

template <int F, bool RELU>
__global__ __launch_bounds__(256) void aggregate_kernel(const float* __restrict__ G,
                                                        const float* __restrict__ dinv,
                                                        const int* __restrict__ row_ptr,
                                                        const int* __restrict__ col,
                                                        const float* __restrict__ bias,
                                                        float* __restrict__ Out, int N) {
    int node = blockIdx.x * 4 + (threadIdx.x >> 6);
    int lane = threadIdx.x & 63;
    if (node >= N) return;
    int beg = row_ptr[node];
    int end = row_ptr[node + 1];

    if (F == 128) {
        const float2* Gp = reinterpret_cast<const float2*>(G);
        float2 a[8];
        a[0] = Gp[(size_t)node * 64 + lane];  // self contribution
#pragma unroll
        for (int i = 1; i < 8; ++i) a[i] = make_float2(0.f, 0.f);
        for (int e = beg; e < end; e += 8) {
            int last = end - 1;
            int jx[8];
#pragma unroll
            for (int i = 0; i < 8; ++i) jx[i] = col[min(e + i, last)];
            float2 v[8];
#pragma unroll
            for (int i = 0; i < 8; ++i) v[i] = Gp[(size_t)jx[i] * 64 + lane];
            a[0].x += v[0].x; a[0].y += v[0].y;
#pragma unroll
            for (int i = 1; i < 8; ++i)
                if (e + i < end) { a[i].x += v[i].x; a[i].y += v[i].y; }
        }
#pragma unroll
        for (int i = 1; i < 8; ++i) { a[0].x += a[i].x; a[0].y += a[i].y; }
        float s = dinv[node];
        float2 bb = reinterpret_cast<const float2*>(bias)[lane];
        float ox = fmaf(s, a[0].x, bb.x);
        float oy = fmaf(s, a[0].y, bb.y);
        if (RELU) {
            ox = fmaxf(ox, 0.f);
            oy = fmaxf(oy, 0.f);
        }
        reinterpret_cast<float2*>(Out)[(size_t)node * 64 + lane] = make_float2(ox, oy);
    } else {  // F == 64
        float a[8];
        a[0] = G[(size_t)node * F + lane];
#pragma unroll
        for (int i = 1; i < 8; ++i) a[i] = 0.f;
        for (int e = beg; e < end; e += 8) {
            int last = end - 1;
            int jx[8];
#pragma unroll
            for (int i = 0; i < 8; ++i) jx[i] = col[min(e + i, last)];
            float v[8];
#pragma unroll
            for (int i = 0; i < 8; ++i) v[i] = G[(size_t)jx[i] * F + lane];
            a[0] += v[0];
#pragma unroll
            for (int i = 1; i < 8; ++i)
                if (e + i < end) a[i] += v[i];
        }
#pragma unroll
        for (int i = 1; i < 8; ++i) a[0] += a[i];
        float o = fmaf(dinv[node], a[0], bias[lane]);
        if (RELU) o = fmaxf(o, 0.f);
        Out[(size_t)node * F + lane] = o;
    }
}

// ---------------- launch ----------------

extern "C" void kernel_launch(void* const* d_in, const int* in_sizes, int n_in,
                              void* d_out, int out_size, void* d_ws, size_t ws_size,
                              hipStream_t stream) {
    const float* x  = (const float*)d_in[0];
    const int*  edge = (const int*)d_in[1];
    const float* W1 = (const float*)d_in[2];
    const float* b1 = (const float*)d_in[3];
    const float* W2 = (const float*)d_in[4];
    const float* b2 = (const float*)d_in[5];
    const float* W3 = (const float*)d_in[6];
    const float* b3 = (const float*)d_in[7];
    float* out = (float*)d_out;

    const int N = NN, E = NE;
    const int* src = edge;
    const int* dst = edge + E;
    const int NBLK = (N + 1023) / 1024;  // 49

    size_t off = 0;
    auto alloc = [&](size_t bytes) {
        void* p = (char*)d_ws + off;
        off = (off + bytes + 255) & ~(size_t)255;
        return p;
    };
    int*   cnt      = (int*)alloc((size_t)N * 4);
    int*   row_ptr  = (int*)alloc((size_t)(N + 1) * 4);
    int*   tmp_ptr  = (int*)alloc((size_t)N * 4);
    int*   colv     = (int*)alloc((size_t)E * 4);
    float* dinv     = (float*)alloc((size_t)N * 4);
    int*   blk_sums = (int*)alloc((size_t)NBLK * 4);
    float* g        = (float*)alloc((size_t)N * 128 * 4);
    float* h        = (float*)alloc((size_t)N * 128 * 4);
    (void)ws_size; (void)in_sizes; (void)n_in; (void)out_size;

    hipMemsetAsync(cnt, 0, (size_t)N * 4, stream);
    count_kernel<<<(E + 255) / 256, 256, 0, stream>>>(dst, cnt, E);
    block_reduce_kernel<<<NBLK, 256, 0, stream>>>(cnt, blk_sums, N);
    scan_sums_kernel<<<1, 64, 0, stream>>>(blk_sums, NBLK);
    block_scan_kernel<<<NBLK, 256, 0, stream>>>(cnt, blk_sums, row_ptr, tmp_ptr, dinv, N, E);
    fill_kernel<<<(E + 255) / 256, 256, 0, stream>>>(src, dst, tmp_ptr, colv, E);

    dim3 gemm_grid((N + 31) / 32);  // 32 rows per block
    dim3 agg_grid((N + 3) / 4);

    gemm_scale_kernel<128><<<gemm_grid, 256, 0, stream>>>(x, W1, dinv, g, N);
    aggregate_kernel<128, true><<<agg_grid, 256, 0, stream>>>(g, dinv, row_ptr, colv, b1, h, N);

    gemm_scale_kernel<128><<<gemm_grid, 256, 0, stream>>>(h, W2, dinv, g, N);
    aggregate_kernel<128, true><<<agg_grid, 256, 0, stream>>>(g, dinv, row_ptr, colv, b2, h, N);

    gemm_scale_kernel<64><<<gemm_grid, 256, 0, stream>>>(h, W3, dinv, g, N);
    aggregate_kernel<64, false><<<agg_grid, 256, 0, stream>>>(g, dinv, row_ptr, colv, b3, out, N);
}

// Round 7
// 444.714 us; speedup vs baseline: 4.0861x; 4.0861x over previous
//
#include <hip/hip_runtime.h>
#include <math.h>

#define NN 50000
#define NE 640000

// ---------------- CSR build ----------------

__global__ void count_kernel(const int* __restrict__ dst, int* __restrict__ cnt, int E) {
    int e = blockIdx.x * blockDim.x + threadIdx.x;
    if (e < E) atomicAdd(&cnt[dst[e]], 1);
}

__global__ __launch_bounds__(256) void block_reduce_kernel(const int* __restrict__ cnt,
                                                           int* __restrict__ blk_sums, int N) {
    __shared__ int red[256];
    int tid = threadIdx.x;
    int base = blockIdx.x * 1024 + tid * 4;
    int s = 0;
    if (base + 3 < N) {
        int4 v = *reinterpret_cast<const int4*>(&cnt[base]);
        s = v.x + v.y + v.z + v.w;
    } else {
        for (int i = 0; i < 4; ++i)
            if (base + i < N) s += cnt[base + i];
    }
    red[tid] = s;
    __syncthreads();
    for (int off = 128; off > 0; off >>= 1) {
        if (tid < off) red[tid] += red[tid + off];
        __syncthreads();
    }
    if (tid == 0) blk_sums[blockIdx.x] = red[0];
}

__global__ __launch_bounds__(64) void scan_sums_kernel(int* __restrict__ blk_sums, int nblk) {
    int lane = threadIdx.x;
    int v = (lane < nblk) ? blk_sums[lane] : 0;
    for (int off = 1; off < 64; off <<= 1) {
        int u = __shfl_up(v, off);
        if (lane >= off) v += u;
    }
    int ex = __shfl_up(v, 1);
    if (lane == 0) ex = 0;
    if (lane < nblk) blk_sums[lane] = ex;
}

__global__ __launch_bounds__(256) void block_scan_kernel(const int* __restrict__ cnt,
                                                         const int* __restrict__ blk_offs,
                                                         int* __restrict__ row_ptr,
                                                         int* __restrict__ tmp_ptr,
                                                         float* __restrict__ dinv,
                                                         int N, int E) {
    __shared__ int warp_sums[4];
    int tid = threadIdx.x;
    int base = blockIdx.x * 1024 + tid * 4;
    int c[4];
    int s = 0;
#pragma unroll
    for (int i = 0; i < 4; ++i) {
        int idx = base + i;
        c[i] = (idx < N) ? cnt[idx] : 0;
        s += c[i];
    }
    int lane = tid & 63;
    int wv = tid >> 6;
    int v = s;
    for (int off = 1; off < 64; off <<= 1) {
        int u = __shfl_up(v, off);
        if (lane >= off) v += u;
    }
    if (lane == 63) warp_sums[wv] = v;
    __syncthreads();
    int woff = 0;
    for (int w = 0; w < wv; ++w) woff += warp_sums[w];
    int run = blk_offs[blockIdx.x] + woff + (v - s);
#pragma unroll
    for (int i = 0; i < 4; ++i) {
        int idx = base + i;
        if (idx < N) {
            row_ptr[idx] = run;
            tmp_ptr[idx] = run;
            run += c[i];
            dinv[idx] = rsqrtf((float)c[i] + 1.0f);
        }
    }
    if (blockIdx.x == 0 && tid == 0) row_ptr[N] = E;
}

__global__ void fill_kernel(const int* __restrict__ src, const int* __restrict__ dst,
                            int* __restrict__ tmp_ptr, int* __restrict__ col, int E) {
    int e = blockIdx.x * blockDim.x + threadIdx.x;
    if (e < E) {
        int d = dst[e];
        int pos = atomicAdd(&tmp_ptr[d], 1);
        col[pos] = src[e];
    }
}

// ---------------- GEMM: G[r][c] = dinv[r] * sum_k X[r][k] * W[k][c], K = 128 ----------------
// No LDS. Thread = RPT rows x 4 cols; 32 rows/block -> 1563 blocks, ~6 waves/SIMD
// grid occupancy; TLP hides W-load (L1/L2) latency. Single-buffered, named loads
// only (NO runtime-indexed buffer arrays -> no scratch). launch_bounds caps VGPR<=128.

template <int NOUT>
__global__ __launch_bounds__(256, 4) void gemm_scale_kernel(const float* __restrict__ X,
                                                            const float* __restrict__ W,
                                                            const float* __restrict__ dinv,
                                                            float* __restrict__ G, int N) {
    constexpr int K = 128;
    constexpr int TXN = NOUT / 4;               // 32 (NOUT=128) / 16 (NOUT=64)
    constexpr int RPT = (NOUT == 128) ? 4 : 2;  // rows per thread
    constexpr int ROWS = (256 / TXN) * RPT;     // 32 rows per block

    int tid = threadIdx.x;
    int tx = tid % TXN;
    int ty = tid / TXN;
    int c0 = tx * 4;
    int r0 = blockIdx.x * ROWS + ty * RPT;

    const float* Xp[RPT];  // compile-time-indexed only
#pragma unroll
    for (int j = 0; j < RPT; ++j) {
        int r = min(r0 + j, N - 1);  // clamp loads; stores guarded below
        Xp[j] = X + (size_t)r * K;
    }

    float acc[RPT][4];
#pragma unroll
    for (int j = 0; j < RPT; ++j)
#pragma unroll
        for (int c = 0; c < 4; ++c) acc[j][c] = 0.f;

#pragma unroll 2
    for (int k = 0; k < K; k += 4) {
        float4 xv[RPT];
#pragma unroll
        for (int j = 0; j < RPT; ++j)
            xv[j] = *reinterpret_cast<const float4*>(Xp[j] + k);
        float4 w0 = *reinterpret_cast<const float4*>(&W[(k + 0) * NOUT + c0]);
        float4 w1 = *reinterpret_cast<const float4*>(&W[(k + 1) * NOUT + c0]);
        float4 w2 = *reinterpret_cast<const float4*>(&W[(k + 2) * NOUT + c0]);
        float4 w3 = *reinterpret_cast<const float4*>(&W[(k + 3) * NOUT + c0]);
#pragma unroll
        for (int j = 0; j < RPT; ++j) {
            const float x0 = reinterpret_cast<const float*>(&xv[j])[0];
            const float x1 = reinterpret_cast<const float*>(&xv[j])[1];
            const float x2 = reinterpret_cast<const float*>(&xv[j])[2];
            const float x3 = reinterpret_cast<const float*>(&xv[j])[3];
            acc[j][0] = fmaf(x0, w0.x, acc[j][0]);
            acc[j][1] = fmaf(x0, w0.y, acc[j][1]);
            acc[j][2] = fmaf(x0, w0.z, acc[j][2]);
            acc[j][3] = fmaf(x0, w0.w, acc[j][3]);
            acc[j][0] = fmaf(x1, w1.x, acc[j][0]);
            acc[j][1] = fmaf(x1, w1.y, acc[j][1]);
            acc[j][2] = fmaf(x1, w1.z, acc[j][2]);
            acc[j][3] = fmaf(x1, w1.w, acc[j][3]);
            acc[j][0] = fmaf(x2, w2.x, acc[j][0]);
            acc[j][1] = fmaf(x2, w2.y, acc[j][1]);
            acc[j][2] = fmaf(x2, w2.z, acc[j][2]);
            acc[j][3] = fmaf(x2, w2.w, acc[j][3]);
            acc[j][0] = fmaf(x3, w3.x, acc[j][0]);
            acc[j][1] = fmaf(x3, w3.y, acc[j][1]);
            acc[j][2] = fmaf(x3, w3.z, acc[j][2]);
            acc[j][3] = fmaf(x3, w3.w, acc[j][3]);
        }
    }

#pragma unroll
    for (int j = 0; j < RPT; ++j) {
        int r = r0 + j;
        if (r < N) {
            float s = dinv[r];
            float4 o;
            o.x = s * acc[j][0];
            o.y = s * acc[j][1];
            o.z = s * acc[j][2];
            o.w = s * acc[j][3];
            *reinterpret_cast<float4*>(&G[(size_t)r * NOUT + c0]) = o;
        }
    }
}

// ---------------- Aggregate: Out[i] = act(dinv[i]*(sum_{j in N(i)} G[j] + G[i]) + b) ----------------
// One wave per node; 8 gathers in flight (8 independent accumulators).

template <int F, bool RELU>
__global__ __launch_bounds__(256) void aggregate_kernel(const float* __restrict__ G,
                                                        const float* __restrict__ dinv,
                                                        const int* __restrict__ row_ptr,
                                                        const int* __restrict__ col,
                                                        const float* __restrict__ bias,
                                                        float* __restrict__ Out, int N) {
    int node = blockIdx.x * 4 + (threadIdx.x >> 6);
    int lane = threadIdx.x & 63;
    if (node >= N) return;
    int beg = row_ptr[node];
    int end = row_ptr[node + 1];

    if (F == 128) {
        const float2* Gp = reinterpret_cast<const float2*>(G);
        float2 a[8];
        a[0] = Gp[(size_t)node * 64 + lane];  // self contribution
#pragma unroll
        for (int i = 1; i < 8; ++i) a[i] = make_float2(0.f, 0.f);
        for (int e = beg; e < end; e += 8) {
            int last = end - 1;
            int jx[8];
#pragma unroll
            for (int i = 0; i < 8; ++i) jx[i] = col[min(e + i, last)];
            float2 v[8];
#pragma unroll
            for (int i = 0; i < 8; ++i) v[i] = Gp[(size_t)jx[i] * 64 + lane];
            a[0].x += v[0].x; a[0].y += v[0].y;
#pragma unroll
            for (int i = 1; i < 8; ++i)
                if (e + i < end) { a[i].x += v[i].x; a[i].y += v[i].y; }
        }
#pragma unroll
        for (int i = 1; i < 8; ++i) { a[0].x += a[i].x; a[0].y += a[i].y; }
        float s = dinv[node];
        float2 bb = reinterpret_cast<const float2*>(bias)[lane];
        float ox = fmaf(s, a[0].x, bb.x);
        float oy = fmaf(s, a[0].y, bb.y);
        if (RELU) {
            ox = fmaxf(ox, 0.f);
            oy = fmaxf(oy, 0.f);
        }
        reinterpret_cast<float2*>(Out)[(size_t)node * 64 + lane] = make_float2(ox, oy);
    } else {  // F == 64
        float a[8];
        a[0] = G[(size_t)node * F + lane];
#pragma unroll
        for (int i = 1; i < 8; ++i) a[i] = 0.f;
        for (int e = beg; e < end; e += 8) {
            int last = end - 1;
            int jx[8];
#pragma unroll
            for (int i = 0; i < 8; ++i) jx[i] = col[min(e + i, last)];
            float v[8];
#pragma unroll
            for (int i = 0; i < 8; ++i) v[i] = G[(size_t)jx[i] * F + lane];
            a[0] += v[0];
#pragma unroll
            for (int i = 1; i < 8; ++i)
                if (e + i < end) a[i] += v[i];
        }
#pragma unroll
        for (int i = 1; i < 8; ++i) a[0] += a[i];
        float o = fmaf(dinv[node], a[0], bias[lane]);
        if (RELU) o = fmaxf(o, 0.f);
        Out[(size_t)node * F + lane] = o;
    }
}

// ---------------- launch ----------------

extern "C" void kernel_launch(void* const* d_in, const int* in_sizes, int n_in,
                              void* d_out, int out_size, void* d_ws, size_t ws_size,
                              hipStream_t stream) {
    const float* x  = (const float*)d_in[0];
    const int*  edge = (const int*)d_in[1];
    const float* W1 = (const float*)d_in[2];
    const float* b1 = (const float*)d_in[3];
    const float* W2 = (const float*)d_in[4];
    const float* b2 = (const float*)d_in[5];
    const float* W3 = (const float*)d_in[6];
    const float* b3 = (const float*)d_in[7];
    float* out = (float*)d_out;

    const int N = NN, E = NE;
    const int* src = edge;
    const int* dst = edge + E;
    const int NBLK = (N + 1023) / 1024;  // 49

    size_t off = 0;
    auto alloc = [&](size_t bytes) {
        void* p = (char*)d_ws + off;
        off = (off + bytes + 255) & ~(size_t)255;
        return p;
    };
    int*   cnt      = (int*)alloc((size_t)N * 4);
    int*   row_ptr  = (int*)alloc((size_t)(N + 1) * 4);
    int*   tmp_ptr  = (int*)alloc((size_t)N * 4);
    int*   colv     = (int*)alloc((size_t)E * 4);
    float* dinv     = (float*)alloc((size_t)N * 4);
    int*   blk_sums = (int*)alloc((size_t)NBLK * 4);
    float* g        = (float*)alloc((size_t)N * 128 * 4);
    float* h        = (float*)alloc((size_t)N * 128 * 4);
    (void)ws_size; (void)in_sizes; (void)n_in; (void)out_size;

    hipMemsetAsync(cnt, 0, (size_t)N * 4, stream);
    count_kernel<<<(E + 255) / 256, 256, 0, stream>>>(dst, cnt, E);
    block_reduce_kernel<<<NBLK, 256, 0, stream>>>(cnt, blk_sums, N);
    scan_sums_kernel<<<1, 64, 0, stream>>>(blk_sums, NBLK);
    block_scan_kernel<<<NBLK, 256, 0, stream>>>(cnt, blk_sums, row_ptr, tmp_ptr, dinv, N, E);
    fill_kernel<<<(E + 255) / 256, 256, 0, stream>>>(src, dst, tmp_ptr, colv, E);

    dim3 gemm_grid((N + 31) / 32);  // 32 rows per block
    dim3 agg_grid((N + 3) / 4);

    gemm_scale_kernel<128><<<gemm_grid, 256, 0, stream>>>(x, W1, dinv, g, N);
    aggregate_kernel<128, true><<<agg_grid, 256, 0, stream>>>(g, dinv, row_ptr, colv, b1, h, N);

    gemm_scale_kernel<128><<<gemm_grid, 256, 0, stream>>>(h, W2, dinv, g, N);
    aggregate_kernel<128, true><<<agg_grid, 256, 0, stream>>>(g, dinv, row_ptr, colv, b2, h, N);

    gemm_scale_kernel<64><<<gemm_grid, 256, 0, stream>>>(h, W3, dinv, g, N);
    aggregate_kernel<64, false><<<agg_grid, 256, 0, stream>>>(g, dinv, row_ptr, colv, b3, out, N);
}

// Round 8
// 434.446 us; speedup vs baseline: 4.1827x; 1.0236x over previous
//
#include <hip/hip_runtime.h>
#include <math.h>

#define NN 50000
#define NE 640000

// ---------------- CSR build ----------------

__global__ void count_kernel(const int* __restrict__ dst, int* __restrict__ cnt, int E) {
    int e = blockIdx.x * blockDim.x + threadIdx.x;
    if (e < E) atomicAdd(&cnt[dst[e]], 1);
}

__global__ __launch_bounds__(256) void block_reduce_kernel(const int* __restrict__ cnt,
                                                           int* __restrict__ blk_sums, int N) {
    __shared__ int red[256];
    int tid = threadIdx.x;
    int base = blockIdx.x * 1024 + tid * 4;
    int s = 0;
    if (base + 3 < N) {
        int4 v = *reinterpret_cast<const int4*>(&cnt[base]);
        s = v.x + v.y + v.z + v.w;
    } else {
        for (int i = 0; i < 4; ++i)
            if (base + i < N) s += cnt[base + i];
    }
    red[tid] = s;
    __syncthreads();
    for (int off = 128; off > 0; off >>= 1) {
        if (tid < off) red[tid] += red[tid + off];
        __syncthreads();
    }
    if (tid == 0) blk_sums[blockIdx.x] = red[0];
}

__global__ __launch_bounds__(64) void scan_sums_kernel(int* __restrict__ blk_sums, int nblk) {
    int lane = threadIdx.x;
    int v = (lane < nblk) ? blk_sums[lane] : 0;
    for (int off = 1; off < 64; off <<= 1) {
        int u = __shfl_up(v, off);
        if (lane >= off) v += u;
    }
    int ex = __shfl_up(v, 1);
    if (lane == 0) ex = 0;
    if (lane < nblk) blk_sums[lane] = ex;
}

__global__ __launch_bounds__(256) void block_scan_kernel(const int* __restrict__ cnt,
                                                         const int* __restrict__ blk_offs,
                                                         int* __restrict__ row_ptr,
                                                         int* __restrict__ tmp_ptr,
                                                         float* __restrict__ dinv,
                                                         int N, int E) {
    __shared__ int warp_sums[4];
    int tid = threadIdx.x;
    int base = blockIdx.x * 1024 + tid * 4;
    int c[4];
    int s = 0;
#pragma unroll
    for (int i = 0; i < 4; ++i) {
        int idx = base + i;
        c[i] = (idx < N) ? cnt[idx] : 0;
        s += c[i];
    }
    int lane = tid & 63;
    int wv = tid >> 6;
    int v = s;
    for (int off = 1; off < 64; off <<= 1) {
        int u = __shfl_up(v, off);
        if (lane >= off) v += u;
    }
    if (lane == 63) warp_sums[wv] = v;
    __syncthreads();
    int woff = 0;
    for (int w = 0; w < wv; ++w) woff += warp_sums[w];
    int run = blk_offs[blockIdx.x] + woff + (v - s);
#pragma unroll
    for (int i = 0; i < 4; ++i) {
        int idx = base + i;
        if (idx < N) {
            row_ptr[idx] = run;
            tmp_ptr[idx] = run;
            run += c[i];
            dinv[idx] = rsqrtf((float)c[i] + 1.0f);
        }
    }
    if (blockIdx.x == 0 && tid == 0) row_ptr[N] = E;
}

__global__ void fill_kernel(const int* __restrict__ src, const int* __restrict__ dst,
                            int* __restrict__ tmp_ptr, int* __restrict__ col, int E) {
    int e = blockIdx.x * blockDim.x + threadIdx.x;
    if (e < E) {
        int d = dst[e];
        int pos = atomicAdd(&tmp_ptr[d], 1);
        col[pos] = src[e];
    }
}

// ---------------- GEMM: G[r][c] = dinv[r] * sum_k X[r][k] * W[k][c], K = 128 ----------------
// No LDS. Each block covers a 64-COLUMN half (blockIdx.y) so its W working set is
// 128k x 64c x 4B = 32KB = exactly L1 -> W loads become L1 hits after first pass
// (round-7 counters: occupancy up, VALU flat => per-CU L1-miss pipe was the
// serializer, W 64KB > 32KB L1 cycled by all waves in lockstep).
// Thread = RPT rows x 4 cols, TXN=16 lanes across the 64 cols.

template <int NOUT, int RPT>
__global__ __launch_bounds__(256, 4) void gemm_scale_kernel(const float* __restrict__ X,
                                                            const float* __restrict__ W,
                                                            const float* __restrict__ dinv,
                                                            float* __restrict__ G, int N) {
    constexpr int K = 128;
    constexpr int ROWS = 16 * RPT;  // 256/16 row-groups * RPT rows

    int tid = threadIdx.x;
    int tx = tid & 15;
    int ty = tid >> 4;
    int c0 = blockIdx.y * 64 + tx * 4;
    int r0 = blockIdx.x * ROWS + ty * RPT;

    const float* Xp[RPT];  // compile-time-indexed only
#pragma unroll
    for (int j = 0; j < RPT; ++j) {
        int r = min(r0 + j, N - 1);  // clamp loads; stores guarded below
        Xp[j] = X + (size_t)r * K;
    }

    float acc[RPT][4];
#pragma unroll
    for (int j = 0; j < RPT; ++j)
#pragma unroll
        for (int c = 0; c < 4; ++c) acc[j][c] = 0.f;

#pragma unroll 2
    for (int k = 0; k < K; k += 4) {
        float4 xv[RPT];
#pragma unroll
        for (int j = 0; j < RPT; ++j)
            xv[j] = *reinterpret_cast<const float4*>(Xp[j] + k);
        float4 w0 = *reinterpret_cast<const float4*>(&W[(k + 0) * NOUT + c0]);
        float4 w1 = *reinterpret_cast<const float4*>(&W[(k + 1) * NOUT + c0]);
        float4 w2 = *reinterpret_cast<const float4*>(&W[(k + 2) * NOUT + c0]);
        float4 w3 = *reinterpret_cast<const float4*>(&W[(k + 3) * NOUT + c0]);
#pragma unroll
        for (int j = 0; j < RPT; ++j) {
            const float x0 = reinterpret_cast<const float*>(&xv[j])[0];
            const float x1 = reinterpret_cast<const float*>(&xv[j])[1];
            const float x2 = reinterpret_cast<const float*>(&xv[j])[2];
            const float x3 = reinterpret_cast<const float*>(&xv[j])[3];
            acc[j][0] = fmaf(x0, w0.x, acc[j][0]);
            acc[j][1] = fmaf(x0, w0.y, acc[j][1]);
            acc[j][2] = fmaf(x0, w0.z, acc[j][2]);
            acc[j][3] = fmaf(x0, w0.w, acc[j][3]);
            acc[j][0] = fmaf(x1, w1.x, acc[j][0]);
            acc[j][1] = fmaf(x1, w1.y, acc[j][1]);
            acc[j][2] = fmaf(x1, w1.z, acc[j][2]);
            acc[j][3] = fmaf(x1, w1.w, acc[j][3]);
            acc[j][0] = fmaf(x2, w2.x, acc[j][0]);
            acc[j][1] = fmaf(x2, w2.y, acc[j][1]);
            acc[j][2] = fmaf(x2, w2.z, acc[j][2]);
            acc[j][3] = fmaf(x2, w2.w, acc[j][3]);
            acc[j][0] = fmaf(x3, w3.x, acc[j][0]);
            acc[j][1] = fmaf(x3, w3.y, acc[j][1]);
            acc[j][2] = fmaf(x3, w3.z, acc[j][2]);
            acc[j][3] = fmaf(x3, w3.w, acc[j][3]);
        }
    }

#pragma unroll
    for (int j = 0; j < RPT; ++j) {
        int r = r0 + j;
        if (r < N) {
            float s = dinv[r];
            float4 o;
            o.x = s * acc[j][0];
            o.y = s * acc[j][1];
            o.z = s * acc[j][2];
            o.w = s * acc[j][3];
            *reinterpret_cast<float4*>(&G[(size_t)r * NOUT + c0]) = o;
        }
    }
}

// ---------------- Aggregate: Out[i] = act(dinv[i]*(sum_{j in N(i)} G[j] + G[i]) + b) ----------------
// One wave per node; 8 gathers in flight (8 independent accumulators).

template <int F, bool RELU>
__global__ __launch_bounds__(256) void aggregate_kernel(const float* __restrict__ G,
                                                        const float* __restrict__ dinv,
                                                        const int* __restrict__ row_ptr,
                                                        const int* __restrict__ col,
                                                        const float* __restrict__ bias,
                                                        float* __restrict__ Out, int N) {
    int node = blockIdx.x * 4 + (threadIdx.x >> 6);
    int lane = threadIdx.x & 63;
    if (node >= N) return;
    int beg = row_ptr[node];
    int end = row_ptr[node + 1];

    if (F == 128) {
        const float2* Gp = reinterpret_cast<const float2*>(G);
        float2 a[8];
        a[0] = Gp[(size_t)node * 64 + lane];  // self contribution
#pragma unroll
        for (int i = 1; i < 8; ++i) a[i] = make_float2(0.f, 0.f);
        for (int e = beg; e < end; e += 8) {
            int last = end - 1;
            int jx[8];
#pragma unroll
            for (int i = 0; i < 8; ++i) jx[i] = col[min(e + i, last)];
            float2 v[8];
#pragma unroll
            for (int i = 0; i < 8; ++i) v[i] = Gp[(size_t)jx[i] * 64 + lane];
            a[0].x += v[0].x; a[0].y += v[0].y;
#pragma unroll
            for (int i = 1; i < 8; ++i)
                if (e + i < end) { a[i].x += v[i].x; a[i].y += v[i].y; }
        }
#pragma unroll
        for (int i = 1; i < 8; ++i) { a[0].x += a[i].x; a[0].y += a[i].y; }
        float s = dinv[node];
        float2 bb = reinterpret_cast<const float2*>(bias)[lane];
        float ox = fmaf(s, a[0].x, bb.x);
        float oy = fmaf(s, a[0].y, bb.y);
        if (RELU) {
            ox = fmaxf(ox, 0.f);
            oy = fmaxf(oy, 0.f);
        }
        reinterpret_cast<float2*>(Out)[(size_t)node * 64 + lane] = make_float2(ox, oy);
    } else {  // F == 64
        float a[8];
        a[0] = G[(size_t)node * F + lane];
#pragma unroll
        for (int i = 1; i < 8; ++i) a[i] = 0.f;
        for (int e = beg; e < end; e += 8) {
            int last = end - 1;
            int jx[8];
#pragma unroll
            for (int i = 0; i < 8; ++i) jx[i] = col[min(e + i, last)];
            float v[8];
#pragma unroll
            for (int i = 0; i < 8; ++i) v[i] = G[(size_t)jx[i] * F + lane];
            a[0] += v[0];
#pragma unroll
            for (int i = 1; i < 8; ++i)
                if (e + i < end) a[i] += v[i];
        }
#pragma unroll
        for (int i = 1; i < 8; ++i) a[0] += a[i];
        float o = fmaf(dinv[node], a[0], bias[lane]);
        if (RELU) o = fmaxf(o, 0.f);
        Out[(size_t)node * F + lane] = o;
    }
}

// ---------------- launch ----------------

extern "C" void kernel_launch(void* const* d_in, const int* in_sizes, int n_in,
                              void* d_out, int out_size, void* d_ws, size_t ws_size,
                              hipStream_t stream) {
    const float* x  = (const float*)d_in[0];
    const int*  edge = (const int*)d_in[1];
    const float* W1 = (const float*)d_in[2];
    const float* b1 = (const float*)d_in[3];
    const float* W2 = (const float*)d_in[4];
    const float* b2 = (const float*)d_in[5];
    const float* W3 = (const float*)d_in[6];
    const float* b3 = (const float*)d_in[7];
    float* out = (float*)d_out;

    const int N = NN, E = NE;
    const int* src = edge;
    const int* dst = edge + E;
    const int NBLK = (N + 1023) / 1024;  // 49

    size_t off = 0;
    auto alloc = [&](size_t bytes) {
        void* p = (char*)d_ws + off;
        off = (off + bytes + 255) & ~(size_t)255;
        return p;
    };
    int*   cnt      = (int*)alloc((size_t)N * 4);
    int*   row_ptr  = (int*)alloc((size_t)(N + 1) * 4);
    int*   tmp_ptr  = (int*)alloc((size_t)N * 4);
    int*   colv     = (int*)alloc((size_t)E * 4);
    float* dinv     = (float*)alloc((size_t)N * 4);
    int*   blk_sums = (int*)alloc((size_t)NBLK * 4);
    float* g        = (float*)alloc((size_t)N * 128 * 4);
    float* h        = (float*)alloc((size_t)N * 128 * 4);
    (void)ws_size; (void)in_sizes; (void)n_in; (void)out_size;

    hipMemsetAsync(cnt, 0, (size_t)N * 4, stream);
    count_kernel<<<(E + 255) / 256, 256, 0, stream>>>(dst, cnt, E);
    block_reduce_kernel<<<NBLK, 256, 0, stream>>>(cnt, blk_sums, N);
    scan_sums_kernel<<<1, 64, 0, stream>>>(blk_sums, NBLK);
    block_scan_kernel<<<NBLK, 256, 0, stream>>>(cnt, blk_sums, row_ptr, tmp_ptr, dinv, N, E);
    fill_kernel<<<(E + 255) / 256, 256, 0, stream>>>(src, dst, tmp_ptr, colv, E);

    // gemm<128>: 64 rows/block, 2 col-halves; gemm<64>: 32 rows/block, 1 col-half
    dim3 gemm128_grid((N + 63) / 64, 2);
    dim3 gemm64_grid((N + 31) / 32, 1);
    dim3 agg_grid((N + 3) / 4);

    gemm_scale_kernel<128, 4><<<gemm128_grid, 256, 0, stream>>>(x, W1, dinv, g, N);
    aggregate_kernel<128, true><<<agg_grid, 256, 0, stream>>>(g, dinv, row_ptr, colv, b1, h, N);

    gemm_scale_kernel<128, 4><<<gemm128_grid, 256, 0, stream>>>(h, W2, dinv, g, N);
    aggregate_kernel<128, true><<<agg_grid, 256, 0, stream>>>(g, dinv, row_ptr, colv, b2, h, N);

    gemm_scale_kernel<64, 2><<<gemm64_grid, 256, 0, stream>>>(h, W3, dinv, g, N);
    aggregate_kernel<64, false><<<agg_grid, 256, 0, stream>>>(g, dinv, row_ptr, colv, b3, out, N);
}

// Round 9
// 334.962 us; speedup vs baseline: 5.4250x; 1.2970x over previous
//
#include <hip/hip_runtime.h>
#include <math.h>

#define NN 50000
#define NE 640000

typedef __bf16 bf16x8 __attribute__((ext_vector_type(8)));
typedef float f32x4 __attribute__((ext_vector_type(4)));

__device__ inline ushort f2bf_rne(float f) {
    uint u = __float_as_uint(f);
    uint r = u + 0x7FFFu + ((u >> 16) & 1u);
    return (ushort)(r >> 16);
}
__device__ inline float bf2f(ushort h) { return __uint_as_float(((uint)h) << 16); }

union BfU {
    ushort u[8];
    bf16x8 v;
};

__device__ inline void cvt8(const float4& a, const float4& b, bf16x8& hi, bf16x8& lo) {
    float f[8] = {a.x, a.y, a.z, a.w, b.x, b.y, b.z, b.w};
    BfU H, L;
#pragma unroll
    for (int i = 0; i < 8; ++i) {
        ushort h = f2bf_rne(f[i]);
        H.u[i] = h;
        L.u[i] = f2bf_rne(f[i] - bf2f(h));
    }
    hi = H.v;
    lo = L.v;
}

// ---------------- CSR build ----------------

__global__ void count_kernel(const int* __restrict__ dst, int* __restrict__ cnt, int E) {
    int e = blockIdx.x * blockDim.x + threadIdx.x;
    if (e < E) atomicAdd(&cnt[dst[e]], 1);
}

__global__ __launch_bounds__(256) void block_reduce_kernel(const int* __restrict__ cnt,
                                                           int* __restrict__ blk_sums, int N) {
    __shared__ int red[256];
    int tid = threadIdx.x;
    int base = blockIdx.x * 1024 + tid * 4;
    int s = 0;
    if (base + 3 < N) {
        int4 v = *reinterpret_cast<const int4*>(&cnt[base]);
        s = v.x + v.y + v.z + v.w;
    } else {
        for (int i = 0; i < 4; ++i)
            if (base + i < N) s += cnt[base + i];
    }
    red[tid] = s;
    __syncthreads();
    for (int off = 128; off > 0; off >>= 1) {
        if (tid < off) red[tid] += red[tid + off];
        __syncthreads();
    }
    if (tid == 0) blk_sums[blockIdx.x] = red[0];
}

__global__ __launch_bounds__(64) void scan_sums_kernel(int* __restrict__ blk_sums, int nblk) {
    int lane = threadIdx.x;
    int v = (lane < nblk) ? blk_sums[lane] : 0;
    for (int off = 1; off < 64; off <<= 1) {
        int u = __shfl_up(v, off);
        if (lane >= off) v += u;
    }
    int ex = __shfl_up(v, 1);
    if (lane == 0) ex = 0;
    if (lane < nblk) blk_sums[lane] = ex;
}

__global__ __launch_bounds__(256) void block_scan_kernel(const int* __restrict__ cnt,
                                                         const int* __restrict__ blk_offs,
                                                         int* __restrict__ row_ptr,
                                                         int* __restrict__ tmp_ptr,
                                                         float* __restrict__ dinv,
                                                         int N, int E) {
    __shared__ int warp_sums[4];
    int tid = threadIdx.x;
    int base = blockIdx.x * 1024 + tid * 4;
    int c[4];
    int s = 0;
#pragma unroll
    for (int i = 0; i < 4; ++i) {
        int idx = base + i;
        c[i] = (idx < N) ? cnt[idx] : 0;
        s += c[i];
    }
    int lane = tid & 63;
    int wv = tid >> 6;
    int v = s;
    for (int off = 1; off < 64; off <<= 1) {
        int u = __shfl_up(v, off);
        if (lane >= off) v += u;
    }
    if (lane == 63) warp_sums[wv] = v;
    __syncthreads();
    int woff = 0;
    for (int w = 0; w < wv; ++w) woff += warp_sums[w];
    int run = blk_offs[blockIdx.x] + woff + (v - s);
#pragma unroll
    for (int i = 0; i < 4; ++i) {
        int idx = base + i;
        if (idx < N) {
            row_ptr[idx] = run;
            tmp_ptr[idx] = run;
            run += c[i];
            dinv[idx] = rsqrtf((float)c[i] + 1.0f);
        }
    }
    if (blockIdx.x == 0 && tid == 0) row_ptr[N] = E;
}

__global__ void fill_kernel(const int* __restrict__ src, const int* __restrict__ dst,
                            int* __restrict__ tmp_ptr, int* __restrict__ col, int E) {
    int e = blockIdx.x * blockDim.x + threadIdx.x;
    if (e < E) {
        int d = dst[e];
        int pos = atomicAdd(&tmp_ptr[d], 1);
        col[pos] = src[e];
    }
}

// ---------------- GEMM via split-bf16 MFMA ----------------
// G[r][c] = dinv[r] * sum_k X[r][k] * W[k][c], K = 128.
// x = hi + lo (bf16 each); x*w ~= hi*hi + lo*hi + hi*lo (lo*lo dropped, ~1e-5).
// Block: 256 thr = 4 waves; 128 rows x 64 cols per block (blockIdx.y = col half).
// W half converted once into LDS as MFMA-tiled bf16 hi/lo (16 tiles x 1KB each).
// Per wave: 2 row-strips of 16 share each B-frag ds_read. mfma_f32_16x16x32_bf16,
// D layout: col = lane&15, row = (lane>>4)*4 + reg (m89-verified).

template <int WSTRIDE>
__global__ __launch_bounds__(256, 3) void gemm_mfma_kernel(const float* __restrict__ X,
                                                           const float* __restrict__ W,
                                                           const float* __restrict__ dinv,
                                                           float* __restrict__ G, int N) {
    __shared__ ushort lds_hi[16 * 512];
    __shared__ ushort lds_lo[16 * 512];
    const int tid = threadIdx.x;
    const int c0 = blockIdx.y * 64;

    // ---- stage W (convert fp32 -> bf16 hi/lo, MFMA-tile layout) ----
    for (int idx = tid; idx < 128 * 64; idx += 256) {
        int k = idx >> 6;
        int n = idx & 63;
        float w = W[k * WSTRIDE + c0 + n];
        ushort h = f2bf_rne(w);
        ushort l = f2bf_rne(w - bf2f(h));
        int kt = k >> 5;
        int t = n >> 4;
        int ln = (n & 15) | (((k >> 3) & 3) << 4);
        int pos = (kt * 4 + t) * 512 + ln * 8 + (k & 7);
        lds_hi[pos] = h;
        lds_lo[pos] = l;
    }
    __syncthreads();

    const int wave = tid >> 6;
    const int lane = tid & 63;
    const int lhi = lane >> 4;  // 0..3
    const int llo = lane & 15;
    const int r0 = blockIdx.x * 128 + wave * 32;

    int ar0 = min(r0 + llo, N - 1);
    int ar1 = min(r0 + 16 + llo, N - 1);
    const float* Xr0 = X + (size_t)ar0 * 128 + lhi * 8;
    const float* Xr1 = X + (size_t)ar1 * 128 + lhi * 8;

    f32x4 acc0[4], acc1[4];
#pragma unroll
    for (int t = 0; t < 4; ++t) {
        acc0[t] = (f32x4){0.f, 0.f, 0.f, 0.f};
        acc1[t] = (f32x4){0.f, 0.f, 0.f, 0.f};
    }

#pragma unroll
    for (int kt = 0; kt < 4; ++kt) {
        const ushort* hp = &lds_hi[kt * 4 * 512 + lane * 8];
        const ushort* lp = &lds_lo[kt * 4 * 512 + lane * 8];
        bf16x8 bh[4], bl[4];
#pragma unroll
        for (int t = 0; t < 4; ++t) {
            bh[t] = *reinterpret_cast<const bf16x8*>(hp + t * 512);
            bl[t] = *reinterpret_cast<const bf16x8*>(lp + t * 512);
        }
        float4 xa0 = *reinterpret_cast<const float4*>(Xr0 + kt * 32);
        float4 xb0 = *reinterpret_cast<const float4*>(Xr0 + kt * 32 + 4);
        float4 xa1 = *reinterpret_cast<const float4*>(Xr1 + kt * 32);
        float4 xb1 = *reinterpret_cast<const float4*>(Xr1 + kt * 32 + 4);
        bf16x8 ah0, al0, ah1, al1;
        cvt8(xa0, xb0, ah0, al0);
        cvt8(xa1, xb1, ah1, al1);
#pragma unroll
        for (int t = 0; t < 4; ++t) {
            acc0[t] = __builtin_amdgcn_mfma_f32_16x16x32_bf16(ah0, bh[t], acc0[t], 0, 0, 0);
            acc1[t] = __builtin_amdgcn_mfma_f32_16x16x32_bf16(ah1, bh[t], acc1[t], 0, 0, 0);
            acc0[t] = __builtin_amdgcn_mfma_f32_16x16x32_bf16(al0, bh[t], acc0[t], 0, 0, 0);
            acc1[t] = __builtin_amdgcn_mfma_f32_16x16x32_bf16(al1, bh[t], acc1[t], 0, 0, 0);
            acc0[t] = __builtin_amdgcn_mfma_f32_16x16x32_bf16(ah0, bl[t], acc0[t], 0, 0, 0);
            acc1[t] = __builtin_amdgcn_mfma_f32_16x16x32_bf16(ah1, bl[t], acc1[t], 0, 0, 0);
        }
    }

    // ---- epilogue: D row = lhi*4 + i, col = t*16 + llo ----
    const int rbase = r0 + lhi * 4;
#pragma unroll
    for (int i = 0; i < 4; ++i) {
        int row = rbase + i;
        if (row < N) {
            float dv = dinv[row];
#pragma unroll
            for (int t = 0; t < 4; ++t)
                G[(size_t)row * WSTRIDE + c0 + t * 16 + llo] = acc0[t][i] * dv;
        }
        int row1 = rbase + 16 + i;
        if (row1 < N) {
            float dv = dinv[row1];
#pragma unroll
            for (int t = 0; t < 4; ++t)
                G[(size_t)row1 * WSTRIDE + c0 + t * 16 + llo] = acc1[t][i] * dv;
        }
    }
}

// ---------------- Aggregate: Out[i] = act(dinv[i]*(sum_{j in N(i)} G[j] + G[i]) + b) ----------------
// One wave per node; 8 gathers in flight (8 independent accumulators).

template <int F, bool RELU>
__global__ __launch_bounds__(256) void aggregate_kernel(const float* __restrict__ G,
                                                        const float* __restrict__ dinv,
                                                        const int* __restrict__ row_ptr,
                                                        const int* __restrict__ col,
                                                        const float* __restrict__ bias,
                                                        float* __restrict__ Out, int N) {
    int node = blockIdx.x * 4 + (threadIdx.x >> 6);
    int lane = threadIdx.x & 63;
    if (node >= N) return;
    int beg = row_ptr[node];
    int end = row_ptr[node + 1];

    if (F == 128) {
        const float2* Gp = reinterpret_cast<const float2*>(G);
        float2 a[8];
        a[0] = Gp[(size_t)node * 64 + lane];  // self contribution
#pragma unroll
        for (int i = 1; i < 8; ++i) a[i] = make_float2(0.f, 0.f);
        for (int e = beg; e < end; e += 8) {
            int last = end - 1;
            int jx[8];
#pragma unroll
            for (int i = 0; i < 8; ++i) jx[i] = col[min(e + i, last)];
            float2 v[8];
#pragma unroll
            for (int i = 0; i < 8; ++i) v[i] = Gp[(size_t)jx[i] * 64 + lane];
            a[0].x += v[0].x; a[0].y += v[0].y;
#pragma unroll
            for (int i = 1; i < 8; ++i)
                if (e + i < end) { a[i].x += v[i].x; a[i].y += v[i].y; }
        }
#pragma unroll
        for (int i = 1; i < 8; ++i) { a[0].x += a[i].x; a[0].y += a[i].y; }
        float s = dinv[node];
        float2 bb = reinterpret_cast<const float2*>(bias)[lane];
        float ox = fmaf(s, a[0].x, bb.x);
        float oy = fmaf(s, a[0].y, bb.y);
        if (RELU) {
            ox = fmaxf(ox, 0.f);
            oy = fmaxf(oy, 0.f);
        }
        reinterpret_cast<float2*>(Out)[(size_t)node * 64 + lane] = make_float2(ox, oy);
    } else {  // F == 64
        float a[8];
        a[0] = G[(size_t)node * F + lane];
#pragma unroll
        for (int i = 1; i < 8; ++i) a[i] = 0.f;
        for (int e = beg; e < end; e += 8) {
            int last = end - 1;
            int jx[8];
#pragma unroll
            for (int i = 0; i < 8; ++i) jx[i] = col[min(e + i, last)];
            float v[8];
#pragma unroll
            for (int i = 0; i < 8; ++i) v[i] = G[(size_t)jx[i] * F + lane];
            a[0] += v[0];
#pragma unroll
            for (int i = 1; i < 8; ++i)
                if (e + i < end) a[i] += v[i];
        }
#pragma unroll
        for (int i = 1; i < 8; ++i) a[0] += a[i];
        float o = fmaf(dinv[node], a[0], bias[lane]);
        if (RELU) o = fmaxf(o, 0.f);
        Out[(size_t)node * F + lane] = o;
    }
}

// ---------------- launch ----------------

extern "C" void kernel_launch(void* const* d_in, const int* in_sizes, int n_in,
                              void* d_out, int out_size, void* d_ws, size_t ws_size,
                              hipStream_t stream) {
    const float* x  = (const float*)d_in[0];
    const int*  edge = (const int*)d_in[1];
    const float* W1 = (const float*)d_in[2];
    const float* b1 = (const float*)d_in[3];
    const float* W2 = (const float*)d_in[4];
    const float* b2 = (const float*)d_in[5];
    const float* W3 = (const float*)d_in[6];
    const float* b3 = (const float*)d_in[7];
    float* out = (float*)d_out;

    const int N = NN, E = NE;
    const int* src = edge;
    const int* dst = edge + E;
    const int NBLK = (N + 1023) / 1024;  // 49

    size_t off = 0;
    auto alloc = [&](size_t bytes) {
        void* p = (char*)d_ws + off;
        off = (off + bytes + 255) & ~(size_t)255;
        return p;
    };
    int*   cnt      = (int*)alloc((size_t)N * 4);
    int*   row_ptr  = (int*)alloc((size_t)(N + 1) * 4);
    int*   tmp_ptr  = (int*)alloc((size_t)N * 4);
    int*   colv     = (int*)alloc((size_t)E * 4);
    float* dinv     = (float*)alloc((size_t)N * 4);
    int*   blk_sums = (int*)alloc((size_t)NBLK * 4);
    float* g        = (float*)alloc((size_t)N * 128 * 4);
    float* h        = (float*)alloc((size_t)N * 128 * 4);
    (void)ws_size; (void)in_sizes; (void)n_in; (void)out_size;

    hipMemsetAsync(cnt, 0, (size_t)N * 4, stream);
    count_kernel<<<(E + 255) / 256, 256, 0, stream>>>(dst, cnt, E);
    block_reduce_kernel<<<NBLK, 256, 0, stream>>>(cnt, blk_sums, N);
    scan_sums_kernel<<<1, 64, 0, stream>>>(blk_sums, NBLK);
    block_scan_kernel<<<NBLK, 256, 0, stream>>>(cnt, blk_sums, row_ptr, tmp_ptr, dinv, N, E);
    fill_kernel<<<(E + 255) / 256, 256, 0, stream>>>(src, dst, tmp_ptr, colv, E);

    dim3 gemm128_grid((N + 127) / 128, 2);
    dim3 gemm64_grid((N + 127) / 128, 1);
    dim3 agg_grid((N + 3) / 4);

    gemm_mfma_kernel<128><<<gemm128_grid, 256, 0, stream>>>(x, W1, dinv, g, N);
    aggregate_kernel<128, true><<<agg_grid, 256, 0, stream>>>(g, dinv, row_ptr, colv, b1, h, N);

    gemm_mfma_kernel<128><<<gemm128_grid, 256, 0, stream>>>(h, W2, dinv, g, N);
    aggregate_kernel<128, true><<<agg_grid, 256, 0, stream>>>(g, dinv, row_ptr, colv, b2, h, N);

    gemm_mfma_kernel<64><<<gemm64_grid, 256, 0, stream>>>(h, W3, dinv, g, N);
    aggregate_kernel<64, false><<<agg_grid, 256, 0, stream>>>(g, dinv, row_ptr, colv, b3, out, N);
}

// Round 10
// 293.060 us; speedup vs baseline: 6.2006x; 1.1430x over previous
//
#include <hip/hip_runtime.h>
#include <hip/hip_fp16.h>
#include <math.h>

#define NN 50000
#define NE 640000

typedef __bf16 bf16x8 __attribute__((ext_vector_type(8)));
typedef float f32x4 __attribute__((ext_vector_type(4)));

__device__ inline ushort f2bf_rne(float f) {
    uint u = __float_as_uint(f);
    uint r = u + 0x7FFFu + ((u >> 16) & 1u);
    return (ushort)(r >> 16);
}
__device__ inline float bf2f(ushort h) { return __uint_as_float(((uint)h) << 16); }

union BfU {
    ushort u[8];
    bf16x8 v;
};

__device__ inline void cvt8(const float4& a, const float4& b, bf16x8& hi, bf16x8& lo) {
    float f[8] = {a.x, a.y, a.z, a.w, b.x, b.y, b.z, b.w};
    BfU H, L;
#pragma unroll
    for (int i = 0; i < 8; ++i) {
        ushort h = f2bf_rne(f[i]);
        H.u[i] = h;
        L.u[i] = f2bf_rne(f[i] - bf2f(h));
    }
    hi = H.v;
    lo = L.v;
}

// ---------------- CSR build ----------------

__global__ void count_kernel(const int* __restrict__ dst, int* __restrict__ cnt, int E) {
    int e = blockIdx.x * blockDim.x + threadIdx.x;
    if (e < E) atomicAdd(&cnt[dst[e]], 1);
}

__global__ __launch_bounds__(256) void block_reduce_kernel(const int* __restrict__ cnt,
                                                           int* __restrict__ blk_sums, int N) {
    __shared__ int red[256];
    int tid = threadIdx.x;
    int base = blockIdx.x * 1024 + tid * 4;
    int s = 0;
    if (base + 3 < N) {
        int4 v = *reinterpret_cast<const int4*>(&cnt[base]);
        s = v.x + v.y + v.z + v.w;
    } else {
        for (int i = 0; i < 4; ++i)
            if (base + i < N) s += cnt[base + i];
    }
    red[tid] = s;
    __syncthreads();
    for (int off = 128; off > 0; off >>= 1) {
        if (tid < off) red[tid] += red[tid + off];
        __syncthreads();
    }
    if (tid == 0) blk_sums[blockIdx.x] = red[0];
}

__global__ __launch_bounds__(64) void scan_sums_kernel(int* __restrict__ blk_sums, int nblk) {
    int lane = threadIdx.x;
    int v = (lane < nblk) ? blk_sums[lane] : 0;
    for (int off = 1; off < 64; off <<= 1) {
        int u = __shfl_up(v, off);
        if (lane >= off) v += u;
    }
    int ex = __shfl_up(v, 1);
    if (lane == 0) ex = 0;
    if (lane < nblk) blk_sums[lane] = ex;
}

__global__ __launch_bounds__(256) void block_scan_kernel(const int* __restrict__ cnt,
                                                         const int* __restrict__ blk_offs,
                                                         int* __restrict__ row_ptr,
                                                         int* __restrict__ tmp_ptr,
                                                         float* __restrict__ dinv,
                                                         int N, int E) {
    __shared__ int warp_sums[4];
    int tid = threadIdx.x;
    int base = blockIdx.x * 1024 + tid * 4;
    int c[4];
    int s = 0;
#pragma unroll
    for (int i = 0; i < 4; ++i) {
        int idx = base + i;
        c[i] = (idx < N) ? cnt[idx] : 0;
        s += c[i];
    }
    int lane = tid & 63;
    int wv = tid >> 6;
    int v = s;
    for (int off = 1; off < 64; off <<= 1) {
        int u = __shfl_up(v, off);
        if (lane >= off) v += u;
    }
    if (lane == 63) warp_sums[wv] = v;
    __syncthreads();
    int woff = 0;
    for (int w = 0; w < wv; ++w) woff += warp_sums[w];
    int run = blk_offs[blockIdx.x] + woff + (v - s);
#pragma unroll
    for (int i = 0; i < 4; ++i) {
        int idx = base + i;
        if (idx < N) {
            row_ptr[idx] = run;
            tmp_ptr[idx] = run;
            run += c[i];
            dinv[idx] = rsqrtf((float)c[i] + 1.0f);
        }
    }
    if (blockIdx.x == 0 && tid == 0) row_ptr[N] = E;
}

__global__ void fill_kernel(const int* __restrict__ src, const int* __restrict__ dst,
                            int* __restrict__ tmp_ptr, int* __restrict__ col, int E) {
    int e = blockIdx.x * blockDim.x + threadIdx.x;
    if (e < E) {
        int d = dst[e];
        int pos = atomicAdd(&tmp_ptr[d], 1);
        col[pos] = src[e];
    }
}

// ---------------- GEMM via split-bf16 MFMA, fp16 output ----------------
// G[r][c] = fp16( dinv[r] * sum_k X[r][k] * W[k][c] ), K = 128.
// x = hi + lo (bf16 each); x*w ~= hi*hi + lo*hi + hi*lo (lo*lo dropped, ~1e-5).
// Block: 256 thr = 4 waves; 128 rows x 64 cols per block (blockIdx.y = col half).
// W half converted once into LDS as MFMA-tiled bf16 hi/lo (16 tiles x 1KB each).
// mfma_f32_16x16x32_bf16; D layout: col = lane&15, row = (lane>>4)*4 + reg (m89).

template <int WSTRIDE>
__global__ __launch_bounds__(256, 3) void gemm_mfma_kernel(const float* __restrict__ X,
                                                           const float* __restrict__ W,
                                                           const float* __restrict__ dinv,
                                                           __half* __restrict__ G, int N) {
    __shared__ ushort lds_hi[16 * 512];
    __shared__ ushort lds_lo[16 * 512];
    const int tid = threadIdx.x;
    const int c0 = blockIdx.y * 64;

    // ---- stage W (convert fp32 -> bf16 hi/lo, MFMA-tile layout) ----
    for (int idx = tid; idx < 128 * 64; idx += 256) {
        int k = idx >> 6;
        int n = idx & 63;
        float w = W[k * WSTRIDE + c0 + n];
        ushort h = f2bf_rne(w);
        ushort l = f2bf_rne(w - bf2f(h));
        int kt = k >> 5;
        int t = n >> 4;
        int ln = (n & 15) | (((k >> 3) & 3) << 4);
        int pos = (kt * 4 + t) * 512 + ln * 8 + (k & 7);
        lds_hi[pos] = h;
        lds_lo[pos] = l;
    }
    __syncthreads();

    const int wave = tid >> 6;
    const int lane = tid & 63;
    const int lhi = lane >> 4;  // 0..3
    const int llo = lane & 15;
    const int r0 = blockIdx.x * 128 + wave * 32;

    int ar0 = min(r0 + llo, N - 1);
    int ar1 = min(r0 + 16 + llo, N - 1);
    const float* Xr0 = X + (size_t)ar0 * 128 + lhi * 8;
    const float* Xr1 = X + (size_t)ar1 * 128 + lhi * 8;

    f32x4 acc0[4], acc1[4];
#pragma unroll
    for (int t = 0; t < 4; ++t) {
        acc0[t] = (f32x4){0.f, 0.f, 0.f, 0.f};
        acc1[t] = (f32x4){0.f, 0.f, 0.f, 0.f};
    }

#pragma unroll
    for (int kt = 0; kt < 4; ++kt) {
        const ushort* hp = &lds_hi[kt * 4 * 512 + lane * 8];
        const ushort* lp = &lds_lo[kt * 4 * 512 + lane * 8];
        bf16x8 bh[4], bl[4];
#pragma unroll
        for (int t = 0; t < 4; ++t) {
            bh[t] = *reinterpret_cast<const bf16x8*>(hp + t * 512);
            bl[t] = *reinterpret_cast<const bf16x8*>(lp + t * 512);
        }
        float4 xa0 = *reinterpret_cast<const float4*>(Xr0 + kt * 32);
        float4 xb0 = *reinterpret_cast<const float4*>(Xr0 + kt * 32 + 4);
        float4 xa1 = *reinterpret_cast<const float4*>(Xr1 + kt * 32);
        float4 xb1 = *reinterpret_cast<const float4*>(Xr1 + kt * 32 + 4);
        bf16x8 ah0, al0, ah1, al1;
        cvt8(xa0, xb0, ah0, al0);
        cvt8(xa1, xb1, ah1, al1);
#pragma unroll
        for (int t = 0; t < 4; ++t) {
            acc0[t] = __builtin_amdgcn_mfma_f32_16x16x32_bf16(ah0, bh[t], acc0[t], 0, 0, 0);
            acc1[t] = __builtin_amdgcn_mfma_f32_16x16x32_bf16(ah1, bh[t], acc1[t], 0, 0, 0);
            acc0[t] = __builtin_amdgcn_mfma_f32_16x16x32_bf16(al0, bh[t], acc0[t], 0, 0, 0);
            acc1[t] = __builtin_amdgcn_mfma_f32_16x16x32_bf16(al1, bh[t], acc1[t], 0, 0, 0);
            acc0[t] = __builtin_amdgcn_mfma_f32_16x16x32_bf16(ah0, bl[t], acc0[t], 0, 0, 0);
            acc1[t] = __builtin_amdgcn_mfma_f32_16x16x32_bf16(ah1, bl[t], acc1[t], 0, 0, 0);
        }
    }

    // ---- epilogue: D row = lhi*4 + i, col = t*16 + llo; store fp16 ----
    const int rbase = r0 + lhi * 4;
#pragma unroll
    for (int i = 0; i < 4; ++i) {
        int row = rbase + i;
        if (row < N) {
            float dv = dinv[row];
#pragma unroll
            for (int t = 0; t < 4; ++t)
                G[(size_t)row * WSTRIDE + c0 + t * 16 + llo] = __float2half_rn(acc0[t][i] * dv);
        }
        int row1 = rbase + 16 + i;
        if (row1 < N) {
            float dv = dinv[row1];
#pragma unroll
            for (int t = 0; t < 4; ++t)
                G[(size_t)row1 * WSTRIDE + c0 + t * 16 + llo] = __float2half_rn(acc1[t][i] * dv);
        }
    }
}

// ---------------- Aggregate: Out[i] = act(dinv[i]*(sum_{j in N(i)} G[j] + G[i]) + b) ----------------
// One wave per node; 8 gathers in flight. G is fp16 (halves gather traffic);
// accumulation fp32; output fp32.

template <int F, bool RELU>
__global__ __launch_bounds__(256) void aggregate_kernel(const __half* __restrict__ G,
                                                        const float* __restrict__ dinv,
                                                        const int* __restrict__ row_ptr,
                                                        const int* __restrict__ col,
                                                        const float* __restrict__ bias,
                                                        float* __restrict__ Out, int N) {
    int node = blockIdx.x * 4 + (threadIdx.x >> 6);
    int lane = threadIdx.x & 63;
    if (node >= N) return;
    int beg = row_ptr[node];
    int end = row_ptr[node + 1];

    if (F == 128) {
        const __half2* Gp = reinterpret_cast<const __half2*>(G);
        float2 a[8];
        a[0] = __half22float2(Gp[(size_t)node * 64 + lane]);  // self contribution
#pragma unroll
        for (int i = 1; i < 8; ++i) a[i] = make_float2(0.f, 0.f);
        for (int e = beg; e < end; e += 8) {
            int last = end - 1;
            int jx[8];
#pragma unroll
            for (int i = 0; i < 8; ++i) jx[i] = col[min(e + i, last)];
            float2 v[8];
#pragma unroll
            for (int i = 0; i < 8; ++i) v[i] = __half22float2(Gp[(size_t)jx[i] * 64 + lane]);
            a[0].x += v[0].x; a[0].y += v[0].y;
#pragma unroll
            for (int i = 1; i < 8; ++i)
                if (e + i < end) { a[i].x += v[i].x; a[i].y += v[i].y; }
        }
#pragma unroll
        for (int i = 1; i < 8; ++i) { a[0].x += a[i].x; a[0].y += a[i].y; }
        float s = dinv[node];
        float2 bb = reinterpret_cast<const float2*>(bias)[lane];
        float ox = fmaf(s, a[0].x, bb.x);
        float oy = fmaf(s, a[0].y, bb.y);
        if (RELU) {
            ox = fmaxf(ox, 0.f);
            oy = fmaxf(oy, 0.f);
        }
        reinterpret_cast<float2*>(Out)[(size_t)node * 64 + lane] = make_float2(ox, oy);
    } else {  // F == 64
        float a[8];
        a[0] = __half2float(G[(size_t)node * F + lane]);
#pragma unroll
        for (int i = 1; i < 8; ++i) a[i] = 0.f;
        for (int e = beg; e < end; e += 8) {
            int last = end - 1;
            int jx[8];
#pragma unroll
            for (int i = 0; i < 8; ++i) jx[i] = col[min(e + i, last)];
            float v[8];
#pragma unroll
            for (int i = 0; i < 8; ++i) v[i] = __half2float(G[(size_t)jx[i] * F + lane]);
            a[0] += v[0];
#pragma unroll
            for (int i = 1; i < 8; ++i)
                if (e + i < end) a[i] += v[i];
        }
#pragma unroll
        for (int i = 1; i < 8; ++i) a[0] += a[i];
        float o = fmaf(dinv[node], a[0], bias[lane]);
        if (RELU) o = fmaxf(o, 0.f);
        Out[(size_t)node * F + lane] = o;
    }
}

// ---------------- launch ----------------

extern "C" void kernel_launch(void* const* d_in, const int* in_sizes, int n_in,
                              void* d_out, int out_size, void* d_ws, size_t ws_size,
                              hipStream_t stream) {
    const float* x  = (const float*)d_in[0];
    const int*  edge = (const int*)d_in[1];
    const float* W1 = (const float*)d_in[2];
    const float* b1 = (const float*)d_in[3];
    const float* W2 = (const float*)d_in[4];
    const float* b2 = (const float*)d_in[5];
    const float* W3 = (const float*)d_in[6];
    const float* b3 = (const float*)d_in[7];
    float* out = (float*)d_out;

    const int N = NN, E = NE;
    const int* src = edge;
    const int* dst = edge + E;
    const int NBLK = (N + 1023) / 1024;  // 49

    size_t off = 0;
    auto alloc = [&](size_t bytes) {
        void* p = (char*)d_ws + off;
        off = (off + bytes + 255) & ~(size_t)255;
        return p;
    };
    int*    cnt      = (int*)alloc((size_t)N * 4);
    int*    row_ptr  = (int*)alloc((size_t)(N + 1) * 4);
    int*    tmp_ptr  = (int*)alloc((size_t)N * 4);
    int*    colv     = (int*)alloc((size_t)E * 4);
    float*  dinv     = (float*)alloc((size_t)N * 4);
    int*    blk_sums = (int*)alloc((size_t)NBLK * 4);
    __half* g        = (__half*)alloc((size_t)N * 128 * 2);
    float*  h        = (float*)alloc((size_t)N * 128 * 4);
    (void)ws_size; (void)in_sizes; (void)n_in; (void)out_size;

    hipMemsetAsync(cnt, 0, (size_t)N * 4, stream);
    count_kernel<<<(E + 255) / 256, 256, 0, stream>>>(dst, cnt, E);
    block_reduce_kernel<<<NBLK, 256, 0, stream>>>(cnt, blk_sums, N);
    scan_sums_kernel<<<1, 64, 0, stream>>>(blk_sums, NBLK);
    block_scan_kernel<<<NBLK, 256, 0, stream>>>(cnt, blk_sums, row_ptr, tmp_ptr, dinv, N, E);
    fill_kernel<<<(E + 255) / 256, 256, 0, stream>>>(src, dst, tmp_ptr, colv, E);

    dim3 gemm128_grid((N + 127) / 128, 2);
    dim3 gemm64_grid((N + 127) / 128, 1);
    dim3 agg_grid((N + 3) / 4);

    gemm_mfma_kernel<128><<<gemm128_grid, 256, 0, stream>>>(x, W1, dinv, g, N);
    aggregate_kernel<128, true><<<agg_grid, 256, 0, stream>>>(g, dinv, row_ptr, colv, b1, h, N);

    gemm_mfma_kernel<128><<<gemm128_grid, 256, 0, stream>>>(h, W2, dinv, g, N);
    aggregate_kernel<128, true><<<agg_grid, 256, 0, stream>>>(g, dinv, row_ptr, colv, b2, h, N);

    gemm_mfma_kernel<64><<<gemm64_grid, 256, 0, stream>>>(h, W3, dinv, g, N);
    aggregate_kernel<64, false><<<agg_grid, 256, 0, stream>>>(g, dinv, row_ptr, colv, b3, out, N);
}